// Round 8
// baseline (407.063 us; speedup 1.0000x reference)
//
#include <hip/hip_runtime.h>
#include <math.h>

#define NMODES 32
#define NPAIR 496
#define TAYLOR_N 12

// T2 matrix in module-scope device memory (d_ws may be zero-sized).
__device__ float2 g_T2[NMODES * NMODES];

__device__ __forceinline__ float2 cmul(float2 a, float2 b) {
    return make_float2(a.x * b.x - a.y * b.y, a.x * b.y + a.y * b.x);
}

// ---------------------------------------------------------------------------
// Setup kernel: one block of 1024 threads builds T2 (32x32 complex).
// (unchanged from the round-0/3/5 PASSING kernels)
// ---------------------------------------------------------------------------
__global__ __launch_bounds__(1024) void setup_kernel(const float* __restrict__ params,
                                                     const float* __restrict__ kappa) {
    __shared__ float2 X[NMODES][NMODES];
    __shared__ float2 R[NMODES][NMODES];
    __shared__ float2 W[NMODES][NMODES];
    __shared__ float2 Aug[NMODES][2 * NMODES];
    __shared__ int sh_s;
    __shared__ float sh_scale;
    __shared__ int sh_piv;
    __shared__ float2 sh_pivrec;

    const int tid = threadIdx.x;
    const int i = tid >> 5;
    const int j = tid & 31;

    // --- build H ---
    float2 h;
    if (i == j) {
        float d;
        if (i < 31) {
            d = params[2 * NPAIR + i];
        } else {
            d = 0.0f;
            for (int r = 0; r < 31; ++r) d -= params[2 * NPAIR + r];
        }
        h = make_float2(d, 0.0f);
    } else {
        int a = (i < j) ? i : j;
        int b = (i < j) ? j : i;
        int idx = 31 * a - (a * (a - 1)) / 2 + (b - a - 1);  // row-major triu
        float re = params[idx];
        float im = params[NPAIR + idx];
        h = (i < j) ? make_float2(re, im) : make_float2(re, -im);
    }
    X[i][j] = h;
    __syncthreads();

    // --- inf-norm (wave 0, parallel rows + shuffle max-reduce) ---
    if (tid < 32) {
        float s = 0.0f;
        for (int c = 0; c < NMODES; ++c) {
            float2 v = X[tid][c];
            s += sqrtf(v.x * v.x + v.y * v.y);
        }
        for (int off = 16; off > 0; off >>= 1)
            s = fmaxf(s, __shfl_down(s, off));
        if (tid == 0) {
            int sc_n = 0;
            float sc = 1.0f;
            while (s > 0.25f && sc_n < 40) { s *= 0.5f; sc *= 0.5f; ++sc_n; }
            sh_s = sc_n;
            sh_scale = sc;
        }
    }
    __syncthreads();

    // --- X = (i*H) * 2^{-s} ---
    {
        float sc = sh_scale;
        float2 v = X[i][j];
        X[i][j] = make_float2(-v.y * sc, v.x * sc);
    }
    __syncthreads();

    // --- Taylor via Horner: R = I; for k=N..1: R = I + (X*R)/k ---
    R[i][j] = make_float2((i == j) ? 1.0f : 0.0f, 0.0f);
    __syncthreads();
    for (int k = TAYLOR_N; k >= 1; --k) {
        float2 acc = make_float2(0.0f, 0.0f);
        for (int kk = 0; kk < NMODES; ++kk) {
            float2 a = X[i][kk];
            float2 b = R[kk][j];
            acc.x = fmaf(a.x, b.x, fmaf(-a.y, b.y, acc.x));
            acc.y = fmaf(a.x, b.y, fmaf(a.y, b.x, acc.y));
        }
        __syncthreads();
        float invk = 1.0f / (float)k;
        R[i][j] = make_float2(((i == j) ? 1.0f : 0.0f) + acc.x * invk, acc.y * invk);
        __syncthreads();
    }

    // --- squarings ---
    {
        int s = sh_s;
        for (int q = 0; q < s; ++q) {
            float2 acc = make_float2(0.0f, 0.0f);
            for (int kk = 0; kk < NMODES; ++kk) {
                float2 a = R[i][kk];
                float2 b = R[kk][j];
                acc.x = fmaf(a.x, b.x, fmaf(-a.y, b.y, acc.x));
                acc.y = fmaf(a.x, b.y, fmaf(a.y, b.x, acc.y));
            }
            __syncthreads();
            R[i][j] = acc;
            __syncthreads();
        }
    }

    // --- W = U^T U (no conjugation) ---
    {
        float2 acc = make_float2(0.0f, 0.0f);
        for (int kk = 0; kk < NMODES; ++kk) {
            float2 a = R[kk][i];
            float2 b = R[kk][j];
            acc.x = fmaf(a.x, b.x, fmaf(-a.y, b.y, acc.x));
            acc.y = fmaf(a.x, b.y, fmaf(a.y, b.x, acc.y));
        }
        W[i][j] = acc;
    }
    __syncthreads();

    // --- augmented [1.1 I - W | W] ---
    {
        float2 w = W[i][j];
        Aug[i][j] = make_float2(((i == j) ? 1.1f : 0.0f) - w.x, -w.y);
        Aug[i][j + NMODES] = w;
    }
    __syncthreads();

    // --- Gauss-Jordan with partial pivoting; right half -> mix ---
    for (int p = 0; p < NMODES; ++p) {
        if (tid < 32) {  // parallel argmax pivot search (wave 0)
            float2 v = Aug[tid][p];
            float mag = (tid >= p) ? (v.x * v.x + v.y * v.y) : -1.0f;
            int idx = tid;
            for (int off = 16; off > 0; off >>= 1) {
                float omg = __shfl_down(mag, off);
                int oi = __shfl_down(idx, off);
                if (omg > mag) { mag = omg; idx = oi; }
            }
            if (tid == 0) sh_piv = idx;
        }
        __syncthreads();
        int piv = sh_piv;
        if (piv != p && i == p) {
            float2 a0 = Aug[p][j], b0 = Aug[piv][j];
            float2 a1 = Aug[p][j + NMODES], b1 = Aug[piv][j + NMODES];
            Aug[p][j] = b0; Aug[piv][j] = a0;
            Aug[p][j + NMODES] = b1; Aug[piv][j + NMODES] = a1;
        }
        __syncthreads();
        if (tid == 0) {
            float2 d = Aug[p][p];
            float den = d.x * d.x + d.y * d.y;
            sh_pivrec = make_float2(d.x / den, -d.y / den);
        }
        __syncthreads();
        if (i == p) {
            float2 pr = sh_pivrec;
            Aug[p][j] = cmul(Aug[p][j], pr);
            Aug[p][j + NMODES] = cmul(Aug[p][j + NMODES], pr);
        }
        __syncthreads();
        float2 f = Aug[i][p];
        __syncthreads();
        if (i != p) {
            float2 rp0 = Aug[p][j];
            float2 rp1 = Aug[p][j + NMODES];
            float2 v0 = Aug[i][j];
            float2 v1 = Aug[i][j + NMODES];
            v0.x -= f.x * rp0.x - f.y * rp0.y;
            v0.y -= f.x * rp0.y + f.y * rp0.x;
            v1.x -= f.x * rp1.x - f.y * rp1.y;
            v1.y -= f.x * rp1.y + f.y * rp1.x;
            Aug[i][j] = v0;
            Aug[i][j + NMODES] = v1;
        }
        __syncthreads();
    }

    // --- T2 ---
    {
        float2 mix = Aug[i][j + NMODES];
        float kk2 = fabsf(kappa[i]) * fabsf(kappa[j]);
        float re = -kk2 * (((i == j) ? 0.5f : 0.0f) + mix.x);
        float im = -kk2 * mix.y;
        g_T2[i * NMODES + j] = make_float2(re, im);
    }
}

// ===========================================================================
// Main ODE kernel — INTRA-BLOCK PIPE-MIX (placement-proof version of R7).
//
// R7's inter-block parity mix showed ZERO gain (896 cyc/eval == pure-DPP
// 907): blocks map to XCDs by blockIdx%8, so parity segregated the types
// across XCDs and every CU ran ONE type. This version pins one DPP wave and
// one LDS wave in the SAME 128-thread workgroup -> same CU guaranteed.
// Per CU (4 blocks): DS load 8x102 -> 4x102 cyc/eval-window; mixed
// instruction streams on each SIMD decorrelate the in-phase stall overlap
// (R5 ledger: wall-busy = 222 cyc/eval of twin-wave stalls).
//
// Changes required for 2-wave legality (everything else byte-identical to
// the passing R0/R5 paths):
//  - LDS path: __syncthreads -> __builtin_amdgcn_wave_barrier(). xbuf is
//    wave-private and per-wave DS ops execute in order on CDNA, so only a
//    compiler fence is needed (the s_barrier was for multi-wave blocks).
//  - DPP path: ainit LDS bounce -> ds_bpermute init (no LDS, no barrier).
// ===========================================================================

// ------------------------------ DPP path (round 5) -------------------------
template<int CTRL>
__device__ __forceinline__ float2 dppshuf(float2 v) {
    return make_float2(
        __int_as_float(__builtin_amdgcn_mov_dpp(__float_as_int(v.x), CTRL, 0xF, 0xF, true)),
        __int_as_float(__builtin_amdgcn_mov_dpp(__float_as_int(v.y), CTRL, 0xF, 0xF, true)));
}

#define QP_X1 0xB1   // quad_perm [1,0,3,2]   == xor 1
#define QP_X2 0x4E   // quad_perm [2,3,0,1]   == xor 2
#define QP_X3 0x1B   // quad_perm [3,2,1,0]   == xor 3
#define HM_X7 0x141  // row_half_mirror       == xor 7  (within 8)
#define RM_XF 0x140  // row_mirror            == xor 15 (within 16)

__device__ __forceinline__ void cfma(float2& acc, float2 c, float2 w) {
    acc.x = fmaf(c.x, w.x, fmaf(-c.y, w.y, acc.x));
    acc.y = fmaf(c.x, w.y, fmaf(c.y, w.x, acc.y));
}

__device__ __forceinline__ float bperm(int idx, float v) {
    return __int_as_float(__builtin_amdgcn_ds_bpermute(idx, __float_as_int(v)));
}

__device__ __forceinline__ float2 feval_dpp(const float2* __restrict__ t2,
                                            float2 z, float om, float nl2,
                                            int bp0, int bp1) {
    // broadcast tree: w[s].lane(p) = z.lane(p^s), depth <= 3
    float2 w1 = dppshuf<QP_X1>(z);
    float2 w2 = dppshuf<QP_X2>(z);
    float2 w3 = dppshuf<QP_X3>(z);
    float2 w7 = dppshuf<HM_X7>(z);
    float2 wF = dppshuf<RM_XF>(z);
    float2 w4 = dppshuf<QP_X3>(w7);   // 7^3 = 4
    float2 w5 = dppshuf<QP_X2>(w7);   // 7^2 = 5
    float2 w6 = dppshuf<QP_X1>(w7);   // 7^1 = 6
    float2 w8 = dppshuf<HM_X7>(wF);   // 15^7 = 8
    float2 wC = dppshuf<QP_X3>(wF);   // 15^3 = 12
    float2 wD = dppshuf<QP_X2>(wF);   // 15^2 = 13
    float2 wE = dppshuf<QP_X1>(wF);   // 15^1 = 14
    float2 w9 = dppshuf<QP_X1>(w8);   // 8^1 = 9
    float2 wA = dppshuf<QP_X2>(w8);   // 8^2 = 10
    float2 wB = dppshuf<QP_X3>(w8);   // 8^3 = 11

    float2 a0 = make_float2(0.0f, 0.0f), a1 = make_float2(0.0f, 0.0f);
    float2 a2 = make_float2(0.0f, 0.0f), a3 = make_float2(0.0f, 0.0f);
    cfma(a0, t2[0],  z);
    cfma(a1, t2[1],  w1);
    cfma(a2, t2[2],  w2);
    cfma(a3, t2[3],  w3);
    cfma(a0, t2[4],  w4);
    cfma(a1, t2[5],  w5);
    cfma(a2, t2[6],  w6);
    cfma(a3, t2[7],  w7);
    cfma(a0, t2[8],  w8);
    cfma(a1, t2[9],  w9);
    cfma(a2, t2[10], wA);
    cfma(a3, t2[11], wB);
    cfma(a0, t2[12], wC);
    cfma(a1, t2[13], wD);
    cfma(a2, t2[14], wE);
    cfma(a3, t2[15], wF);

    float px = (a0.x + a1.x) + (a2.x + a3.x);
    float py = (a0.y + a1.y) + (a2.y + a3.y);
    // partial(out-lo[p]) in lanes p and 32+p; partial(out-hi[p]) in lanes
    // 16+p and 48+p. bp0 = 4*mstar, bp1 = bp0 + 128. (round-3/5 proven)
    float kx = bperm(bp0, px) + bperm(bp1, px);
    float ky = bperm(bp0, py) + bperm(bp1, py);

    float wf = fmaf(nl2, fmaf(z.x, z.x, z.y * z.y), om);
    return make_float2(kx - wf * z.y, ky + wf * z.x);
}

__device__ void ode_dpp(int b, int lane,
                        const float* __restrict__ A0r,
                        const float* __restrict__ A0i,
                        const float* __restrict__ omega,
                        const float* __restrict__ nln,
                        float* __restrict__ out, long long out_size) {
    const int r = lane >> 4;
    const int p = lane & 15;
    const int ho = r & 1;                       // output half this row computes
    const int hr = (r == 1 || r == 2) ? 1 : 0;  // held (ring) half
    const int mstar = 16 * hr + p;              // mode this lane owns
    const int bp0 = 4 * mstar;
    const int bp1 = bp0 + 128;

    float2 t2[16];
    {
        const int row_g = 16 * ho + p;
#pragma unroll
        for (int s = 0; s < 16; ++s)
            t2[s] = g_T2[row_g * 32 + 16 * hr + (p ^ s)];
    }

    const float om = omega[mstar];
    const float nl = nln[0];
    const float nl2 = nl * nl;
    const float dt = 1.0f / 199.0f;
    const float hdt = 0.5f * dt;
    const float sdt = dt / 6.0f;

    // init WITHOUT LDS/barrier (2-wave block): lane l<24 loads A0[l], others
    // hold 1.0; each lane bpermutes its owned mode from lane mstar (0..31).
    float ldr, ldi;
    if (lane < 24) { ldr = A0r[b * 24 + lane]; ldi = A0i[b * 24 + lane]; }
    else           { ldr = 1.0f;               ldi = 0.0f; }
    float2 a = make_float2(bperm(4 * mstar, ldr), bperm(4 * mstar, ldi));

    long long o = (long long)b * 32 + lane;
    if (lane < 32 && o < out_size) out[o] = a.x;

    for (int t = 1; t < 200; ++t) {
        float2 k1 = feval_dpp(t2, a, om, nl2, bp0, bp1);
        float2 z = make_float2(fmaf(hdt, k1.x, a.x), fmaf(hdt, k1.y, a.y));
        float2 k2 = feval_dpp(t2, z, om, nl2, bp0, bp1);
        z = make_float2(fmaf(hdt, k2.x, a.x), fmaf(hdt, k2.y, a.y));
        float2 k3 = feval_dpp(t2, z, om, nl2, bp0, bp1);
        z = make_float2(fmaf(dt, k3.x, a.x), fmaf(dt, k3.y, a.y));
        float2 k4 = feval_dpp(t2, z, om, nl2, bp0, bp1);

        a.x = fmaf(sdt, fmaf(2.0f, k2.x + k3.x, k1.x + k4.x), a.x);
        a.y = fmaf(sdt, fmaf(2.0f, k2.y + k3.y, k1.y + k4.y), a.y);

        o += 65536;  // 2048 * 32
        if (lane < 32 && o < out_size) out[o] = a.x;
    }
}

// ------------------------------ LDS path (round 0) -------------------------
// lane = (m = lane>>1, h = lane&1); half T2 row per lane; halves combine via
// __shfl_xor(.,1). Padded LDS: slot(k) = k + (k>=16 ? 2 : 0).
// Wave-private xbuf: per-wave DS ops are in-order on CDNA, so the stage
// ordering only needs a compiler fence (wave_barrier), not s_barrier.
__device__ __forceinline__ void wb() { __builtin_amdgcn_wave_barrier(); }

__device__ __forceinline__ float2 f_eval_lds(const float4* __restrict__ xq,
                                             float2 ym,
                                             const float2* __restrict__ t2h,
                                             float om, float nl2) {
    float2 acc0 = make_float2(0.0f, 0.0f);
    float2 acc1 = make_float2(0.0f, 0.0f);
#pragma unroll
    for (int j = 0; j < 8; ++j) {
        float4 v = xq[j];  // complex x[h*16+2j], x[h*16+2j+1]
        float2 ta = t2h[2 * j];
        float2 tb = t2h[2 * j + 1];
        acc0.x = fmaf(ta.x, v.x, acc0.x);
        acc0.x = fmaf(-ta.y, v.y, acc0.x);
        acc0.y = fmaf(ta.x, v.y, acc0.y);
        acc0.y = fmaf(ta.y, v.x, acc0.y);
        acc1.x = fmaf(tb.x, v.z, acc1.x);
        acc1.x = fmaf(-tb.y, v.w, acc1.x);
        acc1.y = fmaf(tb.x, v.w, acc1.y);
        acc1.y = fmaf(tb.y, v.z, acc1.y);
    }
    float2 acc = make_float2(acc0.x + acc1.x, acc0.y + acc1.y);
    acc.x += __shfl_xor(acc.x, 1);  // combine K-halves; both lanes get full sum
    acc.y += __shfl_xor(acc.y, 1);
    float w = fmaf(nl2, fmaf(ym.x, ym.x, ym.y * ym.y), om);
    return make_float2(acc.x - w * ym.y, acc.y + w * ym.x);
}

__device__ void ode_lds(int b, int lane,
                        const float* __restrict__ A0r,
                        const float* __restrict__ A0i,
                        const float* __restrict__ omega,
                        const float* __restrict__ nln,
                        float* __restrict__ out, long long out_size) {
    const int m = lane >> 1;
    const int h = lane & 1;

    float2 t2h[16];
#pragma unroll
    for (int j = 0; j < 16; ++j) t2h[j] = g_T2[m * NMODES + h * 16 + j];

    const float om = omega[m];
    const float nl = nln[0];
    const float nl2 = nl * nl;
    const float dt = 1.0f / 199.0f;
    const float hdt = 0.5f * dt;
    const float sdt = dt / 6.0f;

    float2 a;
    if (m < 24) a = make_float2(A0r[b * 24 + m], A0i[b * 24 + m]);
    else        a = make_float2(1.0f, 0.0f);

    __shared__ __align__(16) float2 xbuf[36];  // 32 complex + 2-slot pad at 16
    const int swi = m + ((m >= 16) ? 2 : 0);   // write slot for mode m
    const float4* xq = reinterpret_cast<const float4*>(xbuf) + 9 * h;  // h=1 -> byte 144

    if (h == 0) {
        long long o0 = (long long)b * 32 + m;
        if (o0 < out_size) out[o0] = a.x;
        xbuf[swi] = a;
    }
    wb();

    long long o = (long long)b * 32 + m;
    for (int t = 1; t < 200; ++t) {
        float2 k1 = f_eval_lds(xq, a, t2h, om, nl2);
        float2 y2 = make_float2(fmaf(hdt, k1.x, a.x), fmaf(hdt, k1.y, a.y));
        if (h == 0) xbuf[swi] = y2;
        wb();

        float2 k2 = f_eval_lds(xq, y2, t2h, om, nl2);
        float2 y3 = make_float2(fmaf(hdt, k2.x, a.x), fmaf(hdt, k2.y, a.y));
        if (h == 0) xbuf[swi] = y3;
        wb();

        float2 k3 = f_eval_lds(xq, y3, t2h, om, nl2);
        float2 y4 = make_float2(fmaf(dt, k3.x, a.x), fmaf(dt, k3.y, a.y));
        if (h == 0) xbuf[swi] = y4;
        wb();

        float2 k4 = f_eval_lds(xq, y4, t2h, om, nl2);

        a.x = fmaf(sdt, k1.x + 2.0f * k2.x + 2.0f * k3.x + k4.x, a.x);
        a.y = fmaf(sdt, k1.y + 2.0f * k2.y + 2.0f * k3.y + k4.y, a.y);

        o += 65536;  // 2048 * 32
        if (h == 0) {
            xbuf[swi] = a;
            if (o < out_size) out[o] = a.x;
        }
        wb();
    }
}

// ------------------------------ dispatcher ---------------------------------
// 128-thread block = 2 waves: wave 0 -> DPP path (batch b), wave 1 -> LDS
// path (batch b+1024). Same CU by construction; no cross-wave sync needed.
__global__ __launch_bounds__(128) void ode_kernel(const float* __restrict__ A0r,
                                                  const float* __restrict__ A0i,
                                                  const float* __restrict__ omega,
                                                  const float* __restrict__ nln,
                                                  float* __restrict__ out,
                                                  long long out_size) {
    const int tid = threadIdx.x;
    const int lane = tid & 63;
    const int b = blockIdx.x;
    if (tid < 64) {
        ode_dpp(b, lane, A0r, A0i, omega, nln, out, out_size);
    } else {
        ode_lds(b + 1024, lane, A0r, A0i, omega, nln, out, out_size);
    }
}

extern "C" void kernel_launch(void* const* d_in, const int* in_sizes, int n_in,
                              void* d_out, int out_size, void* d_ws, size_t ws_size,
                              hipStream_t stream) {
    const float* A0r = (const float*)d_in[0];
    const float* A0i = (const float*)d_in[1];
    const float* omega = (const float*)d_in[2];
    const float* kappa = (const float*)d_in[3];
    const float* nln = (const float*)d_in[4];
    const float* params = (const float*)d_in[5];

    setup_kernel<<<1, 1024, 0, stream>>>(params, kappa);
    ode_kernel<<<1024, 128, 0, stream>>>(A0r, A0i, omega, nln,
                                         (float*)d_out, (long long)out_size);
}